// Round 9
// baseline (237.432 us; speedup 1.0000x reference)
//
#include <hip/hip_runtime.h>
#include <hip/hip_fp16.h>

// MPNN, 3 layers, N=50000, E=800000, D=64.
// Fused per layer (layer_kernel):
//   hx[d] = x[d] + sum_{e: dst=d} x[src_e]   -> gathered straight into LDS
//   out   = relu([hx | x] @ Wt^T + bu + (deg+1)*dvec)  (fp16 MFMA, fp32 accum)
// Wt[n][k] = k<64 ? (Wm@Wu_top)[k][n] : Wu_bot[k-64][n]   (fp16, precomputed)
//
// Learned constraints:
//  - NO min-waves launch bound on register-heavy kernels (r4: spilled to scratch).
//  - MFMA A/B share the (g=lane>>4, j) -> k map: feeding both with f(g,j)=8g+j
//    (contiguous 16B loads) computes exact A*B. C/D: col=lane&15, row=4*(lane>>4)+reg.
//  - LDS A-tile rows stride 128B = same-bank; XOR-swizzle 16B-chunk ^= (row&7).
//  - Scattered small stores to a small shared region ping-pong lines across the
//    8 non-coherent per-XCD L2s -> 25x HBM write amplification (r6/r7). Fix:
//    partition the destination range by (blockIdx & 7) so each XCD owns a slice.
//  - rocprof per-dispatch us for tiny dispatches is serialization-inflated (r8:
//    removing a "43us" 195KB memset moved the graph-replay total by ~1us). Only
//    trust dur_us deltas for small-kernel accounting.
//  - Per-lane arrays (myi[8]) must be statically indexed (unrolled) or they
//    spill to scratch.

#define DIM 64

typedef _Float16 f16x8 __attribute__((ext_vector_type(8)));
typedef float f32x4 __attribute__((ext_vector_type(4)));

static __device__ __forceinline__ float lo16(unsigned u) {
  return __half2float(__ushort_as_half((unsigned short)(u & 0xFFFFu)));
}
static __device__ __forceinline__ float hi16(unsigned u) {
  return __half2float(__ushort_as_half((unsigned short)(u >> 16)));
}
static __device__ __forceinline__ unsigned pack16(float a, float b) {
  return (unsigned)__half_as_ushort(__float2half(a)) |
         ((unsigned)__half_as_ushort(__float2half(b)) << 16);
}

// blocks 0..2: fused fp16 weights per layer.  blocks 3..: zero deg[].
__global__ __launch_bounds__(256) void fuse_weights_kernel(
    const float* __restrict__ Wm0, const float* __restrict__ bm0, const float* __restrict__ Wu0,
    const float* __restrict__ Wm1, const float* __restrict__ bm1, const float* __restrict__ Wu1,
    const float* __restrict__ Wm2, const float* __restrict__ bm2, const float* __restrict__ Wu2,
    unsigned short* __restrict__ Wtb, float* __restrict__ dv,
    int* __restrict__ deg, int n) {
  const int l = blockIdx.x;
  if (l >= 3) {
    const int nq = n >> 2;
    const int t0 = (l - 3) * 256 + threadIdx.x;
    const int stride = (gridDim.x - 3) * 256;
    int4* d4 = (int4*)deg;
    for (int i = t0; i < nq; i += stride) d4[i] = make_int4(0, 0, 0, 0);
    return;
  }
  const float* Wm = l == 0 ? Wm0 : l == 1 ? Wm1 : Wm2;
  const float* bm = l == 0 ? bm0 : l == 1 ? bm1 : bm2;
  const float* Wu = l == 0 ? Wu0 : l == 1 ? Wu1 : Wu2;
  __shared__ float sWm[4096];
  __shared__ float sWu[4096];   // top half of Wu (rows 0..63)
  __shared__ float sW1[4096];   // Wm @ Wu_top
  const int tid = threadIdx.x;
  for (int i = tid; i < 4096; i += 256) {
    sWm[i] = Wm[i];
    sWu[i] = Wu[i];
  }
  __syncthreads();
  for (int i = tid; i < 4096; i += 256) {
    const int r = i >> 6, c = i & 63;
    float acc = 0.f;
#pragma unroll
    for (int k = 0; k < 64; ++k) acc = fmaf(sWm[r * 64 + k], sWu[k * 64 + c], acc);
    sW1[i] = acc;
  }
  __syncthreads();
  unsigned short* Wl = Wtb + (size_t)l * 8192;
  for (int i = tid; i < 8192; i += 256) {
    const int ncol = i >> 7, k = i & 127;
    const float v = (k < 64) ? sW1[k * 64 + ncol] : Wu[k * 64 + ncol];
    Wl[i] = __half_as_ushort(__float2half(v));
  }
  if (tid < 64) {
    float acc = 0.f;
#pragma unroll
    for (int k = 0; k < 64; ++k) acc = fmaf(bm[k], sWu[k * 64 + tid], acc);
    dv[l * 64 + tid] = acc;
  }
}

// Merged: fp32->fp16 convert of x (quad i) + degree count (edge i). Both 800k.
__global__ __launch_bounds__(256) void prep_kernel(
    const float* __restrict__ x, unsigned* __restrict__ xb2, int nquads,
    const int* __restrict__ dst, int* __restrict__ deg, int E) {
  const int i = blockIdx.x * 256 + threadIdx.x;
  if (i < nquads) {
    const float4 v = ((const float4*)x)[i];
    xb2[2 * i] = pack16(v.x, v.y);
    xb2[2 * i + 1] = pack16(v.z, v.w);
  }
  if (i < E) atomicAdd(&deg[dst[i]], 1);
}

// 3-phase multi-block exclusive scan of deg -> rowptr (and cursor = rowptr copy)
__global__ __launch_bounds__(256) void scan_sum_kernel(const int* __restrict__ deg,
                                                       int* __restrict__ bsum, int n) {
  const int i = blockIdx.x * 256 + threadIdx.x;
  int v = (i < n) ? deg[i] : 0;
#pragma unroll
  for (int off = 1; off < 64; off <<= 1) v += __shfl_down(v, off, 64);
  __shared__ int ws[4];
  if ((threadIdx.x & 63) == 0) ws[threadIdx.x >> 6] = v;
  __syncthreads();
  if (threadIdx.x == 0) bsum[blockIdx.x] = ws[0] + ws[1] + ws[2] + ws[3];
}

__global__ __launch_bounds__(256) void scan_block_kernel(const int* __restrict__ bsum,
                                                         int* __restrict__ boff, int nb) {
  __shared__ int s[256];
  const int t = threadIdx.x;
  s[t] = (t < nb) ? bsum[t] : 0;
  __syncthreads();
  for (int off = 1; off < 256; off <<= 1) {
    const int v = (t >= off) ? s[t - off] : 0;
    __syncthreads();
    s[t] += v;
    __syncthreads();
  }
  if (t < nb) boff[t] = (t == 0) ? 0 : s[t - 1];
}

__global__ __launch_bounds__(256) void scan_write_kernel(
    const int* __restrict__ deg, const int* __restrict__ boff,
    int* __restrict__ rowptr, int* __restrict__ cursor, int n) {
  __shared__ int s[256];
  const int t = threadIdx.x;
  const int i = blockIdx.x * 256 + t;
  const int v = (i < n) ? deg[i] : 0;
  s[t] = v;
  __syncthreads();
  for (int off = 1; off < 256; off <<= 1) {
    const int u = (t >= off) ? s[t - off] : 0;
    __syncthreads();
    s[t] += u;
    __syncthreads();
  }
  if (i < n) {
    const int excl = boff[blockIdx.x] + s[t] - v;
    rowptr[i] = excl;
    cursor[i] = excl;
    if (i == n - 1) rowptr[n] = excl + v;
  }
}

// XCD-partitioned CSR fill; src loaded only for edges this partition commits.
__global__ __launch_bounds__(256) void fill_kernel(
    const int* __restrict__ src, const int* __restrict__ dst,
    int* __restrict__ cursor, unsigned short* __restrict__ csr16,
    int Epairs, int n, int nd8) {
  const int part = blockIdx.x & 7;
  const int lo = part * nd8;
  const int hi = (part == 7) ? n : lo + nd8;
  const int t0 = (blockIdx.x >> 3) * 256 + threadIdx.x;
  const int stride = (gridDim.x >> 3) * 256;
  for (int t = t0; t < Epairs; t += stride) {
    const int2 d2 = ((const int2*)dst)[t];
    if (d2.x >= lo && d2.x < hi) {
      const int p0 = atomicAdd(&cursor[d2.x], 1);
      csr16[p0] = (unsigned short)src[2 * t];
    }
    if (d2.y >= lo && d2.y < hi) {
      const int p1 = atomicAdd(&cursor[d2.y], 1);
      csr16[p1] = (unsigned short)src[2 * t + 1];
    }
  }
}

// Fused layer: 512 threads, 64 output rows/block.
// Phase 1: each of 8 waves gathers 8 nodes (hx = x + sum of neighbor rows)
//          straight into swizzled LDS (lhx) along with the x row (lx).
// Phase 2: MFMA [lhx | lx] (K=128) x Wt fragments; wave w does row-tile w>>1,
//          col-tiles {0,1} or {2,3}.
template <int OUT_F32>
__global__ __launch_bounds__(512) void layer_kernel(
    const unsigned* __restrict__ xu,   // fp16 x, 2 cols per uint, 32 uints/row
    const int* __restrict__ rowptr, const unsigned short* __restrict__ csr16,
    const unsigned short* __restrict__ Wtb, const float* __restrict__ bu,
    const float* __restrict__ dvec, const int* __restrict__ deg,
    void* __restrict__ outp, int n) {
  __shared__ unsigned lhx[64 * 32];  // 8KB
  __shared__ unsigned lx[64 * 32];   // 8KB
  const int tid = threadIdx.x;
  const int lane = tid & 63;
  const int w = tid >> 6;            // wave 0..7
  const int j = lane & 31, h = lane >> 5;
  const int l15 = lane & 15, lg = lane >> 4;
  const int base = blockIdx.x * 64;

  // B fragments for this wave's two column tiles (global, L2-resident 16KB).
  const int ctbase = (w & 1) * 2;
  f16x8 bfr[2][4];
#pragma unroll
  for (int c = 0; c < 2; ++c)
#pragma unroll
    for (int kq = 0; kq < 4; ++kq)
      bfr[c][kq] = *(const f16x8*)((const char*)Wtb +
                                   ((ctbase + c) * 16 + l15) * 256 + kq * 64 + lg * 16);

  // ---- Phase 1: gather 8 nodes into LDS ----
  const int r0 = w * 8;
  int begs[9];
#pragma unroll
  for (int r = 0; r < 9; ++r) {
    const int idx = base + r0 + r;
    begs[r] = rowptr[idx <= n ? idx : n];
  }
  int myi[8];
#pragma unroll
  for (int r = 0; r < 8; ++r) {
    const int cnt = begs[r + 1] - begs[r];
    myi[r] = (lane < cnt) ? (int)csr16[begs[r] + lane] : 0;
  }
#pragma unroll
  for (int r = 0; r < 8; ++r) {
    const int node = base + r0 + r;
    const int cnt = begs[r + 1] - begs[r];
    const int mi = myi[r];
    const int c64 = cnt > 64 ? 64 : cnt;
    float a0 = 0.f, a1 = 0.f, b0 = 0.f, b1 = 0.f;
    int i = 0;
    for (; i + 7 < c64; i += 8) {  // 4 pair-steps, 4 outstanding loads
      const int sA = __builtin_amdgcn_readlane(mi, i);
      const int sB = __builtin_amdgcn_readlane(mi, i + 1);
      const int sC = __builtin_amdgcn_readlane(mi, i + 2);
      const int sD = __builtin_amdgcn_readlane(mi, i + 3);
      const int sE = __builtin_amdgcn_readlane(mi, i + 4);
      const int sF = __builtin_amdgcn_readlane(mi, i + 5);
      const int sG = __builtin_amdgcn_readlane(mi, i + 6);
      const int sH = __builtin_amdgcn_readlane(mi, i + 7);
      const unsigned u0 = xu[(unsigned)(h ? sB : sA) * 32 + j];
      const unsigned u1 = xu[(unsigned)(h ? sD : sC) * 32 + j];
      const unsigned u2 = xu[(unsigned)(h ? sF : sE) * 32 + j];
      const unsigned u3 = xu[(unsigned)(h ? sH : sG) * 32 + j];
      a0 += lo16(u0); a1 += hi16(u0);
      b0 += lo16(u1); b1 += hi16(u1);
      a0 += lo16(u2); a1 += hi16(u2);
      b0 += lo16(u3); b1 += hi16(u3);
    }
    for (; i + 1 < c64; i += 2) {
      const int sA = __builtin_amdgcn_readlane(mi, i);
      const int sB = __builtin_amdgcn_readlane(mi, i + 1);
      const unsigned u = xu[(unsigned)(h ? sB : sA) * 32 + j];
      a0 += lo16(u); a1 += hi16(u);
    }
    if (i < c64 && h == 0) {  // odd tail: low half only
      const int sA = __builtin_amdgcn_readlane(mi, i);
      const unsigned u = xu[(unsigned)sA * 32 + j];
      a0 += lo16(u); a1 += hi16(u);
    }
    for (int t2 = begs[r] + 64; t2 < begs[r + 1]; ++t2) {  // deg>64: ~never
      if (h == 0) {
        const unsigned u = xu[(unsigned)csr16[t2] * 32 + j];
        a0 += lo16(u); a1 += hi16(u);
      }
    }
    a0 += b0; a1 += b1;
    a0 += __shfl_xor(a0, 32, 64);
    a1 += __shfl_xor(a1, 32, 64);
    if (h == 0) {
      unsigned us = 0;
      if (node < n) us = xu[(unsigned)node * 32 + j];  // self row
      const int rowloc = r0 + r;
      const int ui = rowloc * 32 + (((j >> 2) ^ (rowloc & 7)) << 2) + (j & 3);
      lx[ui] = us;
      lhx[ui] = pack16(a0 + lo16(us), a1 + hi16(us));
    }
  }
  __syncthreads();

  // ---- Phase 2: MFMA ----
  const int rt = (w >> 1) * 16 + l15;  // A row within tile
  f32x4 acc[2] = {0, 0};
#pragma unroll
  for (int kq = 0; kq < 4; ++kq) {
    const unsigned short* mat = (kq < 2) ? (const unsigned short*)lhx
                                         : (const unsigned short*)lx;
    const int chunk = lg + 4 * (kq & 1);
    const int cs = chunk ^ (rt & 7);
    const f16x8 af = *(const f16x8*)((const char*)mat + rt * 128 + cs * 16);
#pragma unroll
    for (int c = 0; c < 2; ++c)
      acc[c] = __builtin_amdgcn_mfma_f32_16x16x32_f16(af, bfr[c][kq], acc[c], 0, 0, 0);
  }
  // epilogue: C/D row = 4*lg + rr, col = (ctbase+c)*16 + l15
#pragma unroll
  for (int rr = 0; rr < 4; ++rr) {
    const int row = base + (w >> 1) * 16 + lg * 4 + rr;
    if (row < n) {
      const float dg = (float)(deg[row] + 1);
#pragma unroll
      for (int c = 0; c < 2; ++c) {
        const int col = (ctbase + c) * 16 + l15;
        float v = acc[c][rr] + bu[col] + dg * dvec[col];
        v = v > 0.f ? v : 0.f;
        if (OUT_F32)
          ((float*)outp)[(size_t)row * 64 + col] = v;
        else
          ((unsigned short*)outp)[(size_t)row * 64 + col] = __half_as_ushort(__float2half(v));
      }
    }
  }
}

extern "C" void kernel_launch(void* const* d_in, const int* in_sizes, int n_in,
                              void* d_out, int out_size, void* d_ws, size_t ws_size,
                              hipStream_t stream) {
  const float* x = (const float*)d_in[0];
  const int* ei = (const int*)d_in[1];
  const int n = in_sizes[0] / DIM;   // 50000
  const int E = in_sizes[1] / 2;     // 800000
  const int* srcp = ei;
  const int* dstp = ei + E;
  const int nb = (n + 255) / 256;

  // Workspace layout (16B alignment maintained; E even)
  unsigned short* xb = (unsigned short*)d_ws;        // n*64 fp16
  unsigned short* yb = xb + (size_t)n * DIM;         // n*64 fp16
  unsigned short* Wtb = yb + (size_t)n * DIM;        // 3*8192 fp16
  unsigned short* csr16 = Wtb + 3 * 8192;            // E ushort
  float* dv = (float*)(csr16 + E);                   // 3*64
  int* deg = (int*)(dv + 3 * 64);                    // n
  int* cursor = deg + n;                             // n
  int* rowptr = cursor + n;                          // n+1
  int* bsum = rowptr + n + 1;                        // 256
  int* boff = bsum + 256;                            // 256

  // One-time prep: fused fp16 weights + deg zeroing (spare blocks); fp16 x +
  // degree (merged); CSR build (XCD-partitioned fill).
  fuse_weights_kernel<<<32, 256, 0, stream>>>(
      (const float*)d_in[2], (const float*)d_in[3], (const float*)d_in[4],
      (const float*)d_in[6], (const float*)d_in[7], (const float*)d_in[8],
      (const float*)d_in[10], (const float*)d_in[11], (const float*)d_in[12],
      Wtb, dv, deg, n);
  const int nquads = n * DIM / 4;
  const int prep_n = nquads > E ? nquads : E;
  prep_kernel<<<(prep_n + 255) / 256, 256, 0, stream>>>(x, (unsigned*)xb, nquads, dstp, deg, E);
  scan_sum_kernel<<<nb, 256, 0, stream>>>(deg, bsum, n);
  scan_block_kernel<<<1, 256, 0, stream>>>(bsum, boff, nb);
  scan_write_kernel<<<nb, 256, 0, stream>>>(deg, boff, rowptr, cursor, n);
  fill_kernel<<<512, 256, 0, stream>>>(srcp, dstp, cursor, csr16, E / 2, n, n / 8);

  // Layer chain (fp16): xb -> yb -> xb -> d_out(fp32)
  const int lblocks = (n + 63) / 64;
  layer_kernel<0><<<lblocks, 512, 0, stream>>>(
      (const unsigned*)xb, rowptr, csr16, Wtb, (const float*)d_in[5], dv, deg, yb, n);
  layer_kernel<0><<<lblocks, 512, 0, stream>>>(
      (const unsigned*)yb, rowptr, csr16, Wtb + 8192, (const float*)d_in[9], dv + 64, deg, xb, n);
  layer_kernel<1><<<lblocks, 512, 0, stream>>>(
      (const unsigned*)xb, rowptr, csr16, Wtb + 16384, (const float*)d_in[13], dv + 128, deg, d_out, n);
}

// Round 10
// 199.905 us; speedup vs baseline: 1.1877x; 1.1877x over previous
//
#include <hip/hip_runtime.h>
#include <hip/hip_fp16.h>

// MPNN, 3 layers, N=50000, E=800000, D=64.
//   hx[d] = x[d] + sum_{e: dst=d} x[src_e]            (CSR gather, fp16 data, fp32 accum)
//   out   = relu([hx | x] @ Wt^T + bu + (deg+1)*dvec) (fp16 MFMA, fp32 accum)
// Wt[n][k] = k<64 ? (Wm@Wu_top)[k][n] : Wu_bot[k-64][n]   (fp16, precomputed)
//
// Learned constraints:
//  - NO min-waves launch bound on register-heavy kernels (r4: 128 weight floats
//    + bound(256,3) -> scratch spill, FETCH 447MB). Mild bounds on lean kernels ok.
//  - Do NOT fuse the latency-bound gather with the MFMA update (r9: fused block
//    serializes gather behind __syncthreads, compiler squeezes VGPR->MLP dies;
//    47.6us/layer vs ~28us split. hx round-trip is only ~4us/layer).
//  - MFMA A/B share the (g=lane>>4, j) -> k map: feeding both with f(g,j)=8g+j
//    (contiguous 16B loads) computes exact A*B. C/D: col=lane&15, row=4*(lane>>4)+reg.
//  - LDS A-tile rows stride 128B = same-bank; XOR-swizzle 16B-chunk ^= (row&7).
//  - Scattered small stores/atomics on a small shared region ping-pong lines
//    across the 8 non-coherent per-XCD L2s -> ~25x HBM write amplification
//    (r6/r7 fill; r10 applies same fix to deg atomics). Fix: partition the
//    destination range by (blockIdx & 7).
//  - rocprof per-dispatch us for tiny dispatches is serialization-inflated (r8).
//  - Per-lane arrays must be statically indexed or they spill to scratch.

#define DIM 64

typedef _Float16 f16x8 __attribute__((ext_vector_type(8)));
typedef float f32x4 __attribute__((ext_vector_type(4)));

static __device__ __forceinline__ float lo16(unsigned u) {
  return __half2float(__ushort_as_half((unsigned short)(u & 0xFFFFu)));
}
static __device__ __forceinline__ float hi16(unsigned u) {
  return __half2float(__ushort_as_half((unsigned short)(u >> 16)));
}
static __device__ __forceinline__ unsigned pack16(float a, float b) {
  return (unsigned)__half_as_ushort(__float2half(a)) |
         ((unsigned)__half_as_ushort(__float2half(b)) << 16);
}

// blocks 0..2: fused fp16 weights per layer.  blocks 3..: zero deg[].
__global__ __launch_bounds__(256) void fuse_weights_kernel(
    const float* __restrict__ Wm0, const float* __restrict__ bm0, const float* __restrict__ Wu0,
    const float* __restrict__ Wm1, const float* __restrict__ bm1, const float* __restrict__ Wu1,
    const float* __restrict__ Wm2, const float* __restrict__ bm2, const float* __restrict__ Wu2,
    unsigned short* __restrict__ Wtb, float* __restrict__ dv,
    int* __restrict__ deg, int n) {
  const int l = blockIdx.x;
  if (l >= 3) {
    const int nq = n >> 2;
    const int t0 = (l - 3) * 256 + threadIdx.x;
    const int stride = (gridDim.x - 3) * 256;
    int4* d4 = (int4*)deg;
    for (int i = t0; i < nq; i += stride) d4[i] = make_int4(0, 0, 0, 0);
    return;
  }
  const float* Wm = l == 0 ? Wm0 : l == 1 ? Wm1 : Wm2;
  const float* bm = l == 0 ? bm0 : l == 1 ? bm1 : bm2;
  const float* Wu = l == 0 ? Wu0 : l == 1 ? Wu1 : Wu2;
  __shared__ float sWm[4096];
  __shared__ float sWu[4096];   // top half of Wu (rows 0..63)
  __shared__ float sW1[4096];   // Wm @ Wu_top
  const int tid = threadIdx.x;
  for (int i = tid; i < 4096; i += 256) {
    sWm[i] = Wm[i];
    sWu[i] = Wu[i];
  }
  __syncthreads();
  for (int i = tid; i < 4096; i += 256) {
    const int r = i >> 6, c = i & 63;
    float acc = 0.f;
#pragma unroll
    for (int k = 0; k < 64; ++k) acc = fmaf(sWm[r * 64 + k], sWu[k * 64 + c], acc);
    sW1[i] = acc;
  }
  __syncthreads();
  unsigned short* Wl = Wtb + (size_t)l * 8192;
  for (int i = tid; i < 8192; i += 256) {
    const int ncol = i >> 7, k = i & 127;
    const float v = (k < 64) ? sW1[k * 64 + ncol] : Wu[k * 64 + ncol];
    Wl[i] = __half_as_ushort(__float2half(v));
  }
  if (tid < 64) {
    float acc = 0.f;
#pragma unroll
    for (int k = 0; k < 64; ++k) acc = fmaf(bm[k], sWu[k * 64 + tid], acc);
    dv[l * 64 + tid] = acc;
  }
}

// Merged: fp32->fp16 convert (full-grid stride) + XCD-partitioned degree count.
__global__ __launch_bounds__(256) void prep_kernel(
    const float* __restrict__ x, unsigned* __restrict__ xb2, int nquads,
    const int* __restrict__ dst, int* __restrict__ deg,
    int Epairs, int n, int nd8) {
  const int gsz = gridDim.x * 256;
  for (int i = blockIdx.x * 256 + threadIdx.x; i < nquads; i += gsz) {
    const float4 v = ((const float4*)x)[i];
    xb2[2 * i] = pack16(v.x, v.y);
    xb2[2 * i + 1] = pack16(v.z, v.w);
  }
  // degree count, partitioned so each deg line is owned by one XCD
  const int part = blockIdx.x & 7;
  const int lo = part * nd8;
  const int hi = (part == 7) ? n : lo + nd8;
  const int t0 = (blockIdx.x >> 3) * 256 + threadIdx.x;
  const int stride = (gridDim.x >> 3) * 256;
  for (int t = t0; t < Epairs; t += stride) {
    const int2 d2 = ((const int2*)dst)[t];
    if (d2.x >= lo && d2.x < hi) atomicAdd(&deg[d2.x], 1);
    if (d2.y >= lo && d2.y < hi) atomicAdd(&deg[d2.y], 1);
  }
}

// 3-phase multi-block exclusive scan of deg -> rowptr (and cursor = rowptr copy)
__global__ __launch_bounds__(256) void scan_sum_kernel(const int* __restrict__ deg,
                                                       int* __restrict__ bsum, int n) {
  const int i = blockIdx.x * 256 + threadIdx.x;
  int v = (i < n) ? deg[i] : 0;
#pragma unroll
  for (int off = 1; off < 64; off <<= 1) v += __shfl_down(v, off, 64);
  __shared__ int ws[4];
  if ((threadIdx.x & 63) == 0) ws[threadIdx.x >> 6] = v;
  __syncthreads();
  if (threadIdx.x == 0) bsum[blockIdx.x] = ws[0] + ws[1] + ws[2] + ws[3];
}

__global__ __launch_bounds__(256) void scan_block_kernel(const int* __restrict__ bsum,
                                                         int* __restrict__ boff, int nb) {
  __shared__ int s[256];
  const int t = threadIdx.x;
  s[t] = (t < nb) ? bsum[t] : 0;
  __syncthreads();
  for (int off = 1; off < 256; off <<= 1) {
    const int v = (t >= off) ? s[t - off] : 0;
    __syncthreads();
    s[t] += v;
    __syncthreads();
  }
  if (t < nb) boff[t] = (t == 0) ? 0 : s[t - 1];
}

__global__ __launch_bounds__(256) void scan_write_kernel(
    const int* __restrict__ deg, const int* __restrict__ boff,
    int* __restrict__ rowptr, int* __restrict__ cursor, int n) {
  __shared__ int s[256];
  const int t = threadIdx.x;
  const int i = blockIdx.x * 256 + t;
  const int v = (i < n) ? deg[i] : 0;
  s[t] = v;
  __syncthreads();
  for (int off = 1; off < 256; off <<= 1) {
    const int u = (t >= off) ? s[t - off] : 0;
    __syncthreads();
    s[t] += u;
    __syncthreads();
  }
  if (i < n) {
    const int excl = boff[blockIdx.x] + s[t] - v;
    rowptr[i] = excl;
    cursor[i] = excl;
    if (i == n - 1) rowptr[n] = excl + v;
  }
}

// XCD-partitioned CSR fill; src loaded only for edges this partition commits.
__global__ __launch_bounds__(256) void fill_kernel(
    const int* __restrict__ src, const int* __restrict__ dst,
    int* __restrict__ cursor, unsigned short* __restrict__ csr16,
    int Epairs, int n, int nd8) {
  const int part = blockIdx.x & 7;
  const int lo = part * nd8;
  const int hi = (part == 7) ? n : lo + nd8;
  const int t0 = (blockIdx.x >> 3) * 256 + threadIdx.x;
  const int stride = (gridDim.x >> 3) * 256;
  for (int t = t0; t < Epairs; t += stride) {
    const int2 d2 = ((const int2*)dst)[t];
    if (d2.x >= lo && d2.x < hi) {
      const int p0 = atomicAdd(&cursor[d2.x], 1);
      csr16[p0] = (unsigned short)src[2 * t];
    }
    if (d2.y >= lo && d2.y < hi) {
      const int p1 = atomicAdd(&cursor[d2.y], 1);
      csr16[p1] = (unsigned short)src[2 * t + 1];
    }
  }
}

// One wave per node, fp16 rows. Each load fetches TWO neighbor rows (half-wave
// h picks the neighbor, 32 lanes x uint = one 128B row). 16-wide top loop keeps
// 8 loads in flight (deg ~Poisson(16), so most edges take this path).
__global__ __launch_bounds__(256, 6) void gather_kernel(
    const unsigned* __restrict__ xu,   // fp16 x, 2 cols per uint, 32 uints/row
    const int* __restrict__ rowptr, const unsigned short* __restrict__ csr16,
    unsigned* __restrict__ hxu, int n) {
  const int lane = threadIdx.x & 63;
  const int j = lane & 31;
  const int h = lane >> 5;
  const int wid = (blockIdx.x * 256 + threadIdx.x) >> 6;
  const int nwaves = (gridDim.x * 256) >> 6;
  for (int node = wid; node < n; node += nwaves) {
    const int nodeu = __builtin_amdgcn_readfirstlane(node);
    const int beg = rowptr[nodeu];
    const int end = rowptr[nodeu + 1];
    const int cnt = end - beg;
    int myi = 0;
    if (lane < cnt) myi = (int)csr16[beg + lane];
    const int c64 = cnt > 64 ? 64 : cnt;
    float a0 = 0.f, a1 = 0.f, b0 = 0.f, b1 = 0.f;
    float c0 = 0.f, c1 = 0.f, d0 = 0.f, d1 = 0.f;
    int i = 0;
    for (; i + 15 < c64; i += 16) {  // 8 outstanding loads
      const int s0 = __builtin_amdgcn_readlane(myi, i);
      const int s1 = __builtin_amdgcn_readlane(myi, i + 1);
      const int s2 = __builtin_amdgcn_readlane(myi, i + 2);
      const int s3 = __builtin_amdgcn_readlane(myi, i + 3);
      const int s4 = __builtin_amdgcn_readlane(myi, i + 4);
      const int s5 = __builtin_amdgcn_readlane(myi, i + 5);
      const int s6 = __builtin_amdgcn_readlane(myi, i + 6);
      const int s7 = __builtin_amdgcn_readlane(myi, i + 7);
      const int s8 = __builtin_amdgcn_readlane(myi, i + 8);
      const int s9 = __builtin_amdgcn_readlane(myi, i + 9);
      const int s10 = __builtin_amdgcn_readlane(myi, i + 10);
      const int s11 = __builtin_amdgcn_readlane(myi, i + 11);
      const int s12 = __builtin_amdgcn_readlane(myi, i + 12);
      const int s13 = __builtin_amdgcn_readlane(myi, i + 13);
      const int s14 = __builtin_amdgcn_readlane(myi, i + 14);
      const int s15 = __builtin_amdgcn_readlane(myi, i + 15);
      const unsigned u0 = xu[(unsigned)(h ? s1 : s0) * 32 + j];
      const unsigned u1 = xu[(unsigned)(h ? s3 : s2) * 32 + j];
      const unsigned u2 = xu[(unsigned)(h ? s5 : s4) * 32 + j];
      const unsigned u3 = xu[(unsigned)(h ? s7 : s6) * 32 + j];
      const unsigned u4 = xu[(unsigned)(h ? s9 : s8) * 32 + j];
      const unsigned u5 = xu[(unsigned)(h ? s11 : s10) * 32 + j];
      const unsigned u6 = xu[(unsigned)(h ? s13 : s12) * 32 + j];
      const unsigned u7 = xu[(unsigned)(h ? s15 : s14) * 32 + j];
      a0 += lo16(u0); a1 += hi16(u0);
      b0 += lo16(u1); b1 += hi16(u1);
      c0 += lo16(u2); c1 += hi16(u2);
      d0 += lo16(u3); d1 += hi16(u3);
      a0 += lo16(u4); a1 += hi16(u4);
      b0 += lo16(u5); b1 += hi16(u5);
      c0 += lo16(u6); c1 += hi16(u6);
      d0 += lo16(u7); d1 += hi16(u7);
    }
    for (; i + 7 < c64; i += 8) {  // 4 outstanding loads
      const int s0 = __builtin_amdgcn_readlane(myi, i);
      const int s1 = __builtin_amdgcn_readlane(myi, i + 1);
      const int s2 = __builtin_amdgcn_readlane(myi, i + 2);
      const int s3 = __builtin_amdgcn_readlane(myi, i + 3);
      const int s4 = __builtin_amdgcn_readlane(myi, i + 4);
      const int s5 = __builtin_amdgcn_readlane(myi, i + 5);
      const int s6 = __builtin_amdgcn_readlane(myi, i + 6);
      const int s7 = __builtin_amdgcn_readlane(myi, i + 7);
      const unsigned u0 = xu[(unsigned)(h ? s1 : s0) * 32 + j];
      const unsigned u1 = xu[(unsigned)(h ? s3 : s2) * 32 + j];
      const unsigned u2 = xu[(unsigned)(h ? s5 : s4) * 32 + j];
      const unsigned u3 = xu[(unsigned)(h ? s7 : s6) * 32 + j];
      a0 += lo16(u0); a1 += hi16(u0);
      b0 += lo16(u1); b1 += hi16(u1);
      c0 += lo16(u2); c1 += hi16(u2);
      d0 += lo16(u3); d1 += hi16(u3);
    }
    for (; i + 1 < c64; i += 2) {
      const int s0 = __builtin_amdgcn_readlane(myi, i);
      const int s1 = __builtin_amdgcn_readlane(myi, i + 1);
      const unsigned u = xu[(unsigned)(h ? s1 : s0) * 32 + j];
      a0 += lo16(u); a1 += hi16(u);
    }
    if (i < c64 && h == 0) {  // odd tail: low half only
      const int s0 = __builtin_amdgcn_readlane(myi, i);
      const unsigned u = xu[(unsigned)s0 * 32 + j];
      a0 += lo16(u); a1 += hi16(u);
    }
    for (int t2 = beg + 64; t2 < end; ++t2) {  // deg>64: ~never
      if (h == 0) {
        const unsigned u = xu[(unsigned)csr16[t2] * 32 + j];
        a0 += lo16(u); a1 += hi16(u);
      }
    }
    a0 = (a0 + b0) + (c0 + d0);
    a1 = (a1 + b1) + (c1 + d1);
    a0 += __shfl_xor(a0, 32, 64);
    a1 += __shfl_xor(a1, 32, 64);
    if (h == 0) {
      const unsigned us = xu[(unsigned)nodeu * 32 + j];  // self
      hxu[(unsigned)nodeu * 32 + j] = pack16(a0 + lo16(us), a1 + hi16(us));
    }
  }
}

// 64 rows per block (4 waves x 16). A = [hx | x] (K=128) staged in swizzled
// LDS; B = Wt[n][k] fragments loaded as contiguous 16B; 16 MFMAs per wave.
template <int OUT_F32>
__global__ __launch_bounds__(256) void gemm_kernel(
    const unsigned short* __restrict__ hxb, const unsigned short* __restrict__ xb,
    const unsigned short* __restrict__ Wtb, const float* __restrict__ bu,
    const float* __restrict__ dvec, const int* __restrict__ deg,
    void* __restrict__ outp, int n) {
  __shared__ unsigned short lhx[64 * 64];
  __shared__ unsigned short lx[64 * 64];
  const int tid = threadIdx.x;
  const int base = blockIdx.x * 64;
  {
    const uint4* ghx = (const uint4*)hxb;
    const uint4* gx = (const uint4*)xb;
    uint4* shx = (uint4*)lhx;
    uint4* sx = (uint4*)lx;
    for (int t = tid; t < 512; t += 256) {
      const int row = t >> 3, c = t & 7;
      const int grow = base + row;
      uint4 vh = make_uint4(0, 0, 0, 0), vx = make_uint4(0, 0, 0, 0);
      if (grow < n) {
        vh = ghx[(size_t)grow * 8 + c];
        vx = gx[(size_t)grow * 8 + c];
      }
      const int cs = c ^ (row & 7);
      shx[row * 8 + cs] = vh;
      sx[row * 8 + cs] = vx;
    }
  }
  const int lane = tid & 63;
  const int w = tid >> 6;
  const int l15 = lane & 15, lg = lane >> 4;
  f16x8 bfr[16];
#pragma unroll
  for (int ct = 0; ct < 4; ++ct)
#pragma unroll
    for (int kq = 0; kq < 4; ++kq)
      bfr[ct * 4 + kq] = *(const f16x8*)((const char*)Wtb + (ct * 16 + l15) * 256 + kq * 64 + lg * 16);
  __syncthreads();
  f32x4 acc[4] = {0, 0, 0, 0};
  const int rt = w * 16 + l15;
#pragma unroll
  for (int kq = 0; kq < 4; ++kq) {
    const unsigned short* mat = (kq < 2) ? lhx : lx;
    const int chunk = lg + 4 * (kq & 1);
    const int cs = chunk ^ (rt & 7);
    const f16x8 af = *(const f16x8*)((const char*)mat + rt * 128 + cs * 16);
#pragma unroll
    for (int ct = 0; ct < 4; ++ct)
      acc[ct] = __builtin_amdgcn_mfma_f32_16x16x32_f16(af, bfr[ct * 4 + kq], acc[ct], 0, 0, 0);
  }
#pragma unroll
  for (int r = 0; r < 4; ++r) {
    const int row = base + w * 16 + lg * 4 + r;
    if (row < n) {
      const float dg = (float)(deg[row] + 1);
#pragma unroll
      for (int ct = 0; ct < 4; ++ct) {
        const int col = ct * 16 + l15;
        float v = acc[ct][r] + bu[col] + dg * dvec[col];
        v = v > 0.f ? v : 0.f;
        if (OUT_F32)
          ((float*)outp)[(size_t)row * 64 + col] = v;
        else
          ((unsigned short*)outp)[(size_t)row * 64 + col] = __half_as_ushort(__float2half(v));
      }
    }
  }
}

extern "C" void kernel_launch(void* const* d_in, const int* in_sizes, int n_in,
                              void* d_out, int out_size, void* d_ws, size_t ws_size,
                              hipStream_t stream) {
  const float* x = (const float*)d_in[0];
  const int* ei = (const int*)d_in[1];
  const int n = in_sizes[0] / DIM;   // 50000
  const int E = in_sizes[1] / 2;     // 800000
  const int* srcp = ei;
  const int* dstp = ei + E;
  const int nb = (n + 255) / 256;

  // Workspace layout (16B alignment maintained; E even)
  unsigned short* xb = (unsigned short*)d_ws;        // n*64 fp16
  unsigned short* hxb = xb + (size_t)n * DIM;        // n*64 fp16
  unsigned short* yb = hxb + (size_t)n * DIM;        // n*64 fp16
  unsigned short* Wtb = yb + (size_t)n * DIM;        // 3*8192 fp16
  unsigned short* csr16 = Wtb + 3 * 8192;            // E ushort
  float* dv = (float*)(csr16 + E);                   // 3*64
  int* deg = (int*)(dv + 3 * 64);                    // n
  int* cursor = deg + n;                             // n
  int* rowptr = cursor + n;                          // n+1
  int* bsum = rowptr + n + 1;                        // 256
  int* boff = bsum + 256;                            // 256

  // One-time prep: fused fp16 weights + deg zeroing (spare blocks); fp16 x +
  // partitioned degree count (merged); CSR build (XCD-partitioned fill).
  fuse_weights_kernel<<<32, 256, 0, stream>>>(
      (const float*)d_in[2], (const float*)d_in[3], (const float*)d_in[4],
      (const float*)d_in[6], (const float*)d_in[7], (const float*)d_in[8],
      (const float*)d_in[10], (const float*)d_in[11], (const float*)d_in[12],
      Wtb, dv, deg, n);
  const int nquads = n * DIM / 4;
  prep_kernel<<<512, 256, 0, stream>>>(x, (unsigned*)xb, nquads, dstp, deg, E / 2, n, n / 8);
  scan_sum_kernel<<<nb, 256, 0, stream>>>(deg, bsum, n);
  scan_block_kernel<<<1, 256, 0, stream>>>(bsum, boff, nb);
  scan_write_kernel<<<nb, 256, 0, stream>>>(deg, boff, rowptr, cursor, n);
  fill_kernel<<<512, 256, 0, stream>>>(srcp, dstp, cursor, csr16, E / 2, n, n / 8);

  // Layer chain (fp16): xb -> yb -> xb -> d_out(fp32)
  const int gblocks = (n + 63) / 64;
  gather_kernel<<<2048, 256, 0, stream>>>((const unsigned*)xb, rowptr, csr16, (unsigned*)hxb, n);
  gemm_kernel<0><<<gblocks, 256, 0, stream>>>(hxb, xb, Wtb, (const float*)d_in[5], dv, deg, yb, n);
  gather_kernel<<<2048, 256, 0, stream>>>((const unsigned*)yb, rowptr, csr16, (unsigned*)hxb, n);
  gemm_kernel<0><<<gblocks, 256, 0, stream>>>(hxb, yb, Wtb + 8192, (const float*)d_in[9], dv + 64, deg, xb, n);
  gather_kernel<<<2048, 256, 0, stream>>>((const unsigned*)xb, rowptr, csr16, (unsigned*)hxb, n);
  gemm_kernel<1><<<gblocks, 256, 0, stream>>>(hxb, xb, Wtb + 16384, (const float*)d_in[13], dv + 128, deg, d_out, n);
}

// Round 11
// 171.061 us; speedup vs baseline: 1.3880x; 1.1686x over previous
//
#include <hip/hip_runtime.h>
#include <hip/hip_fp16.h>

// MPNN, 3 layers, N=50000, E=800000, D=64.
//   hx[d] = x[d] + sum_{e: dst=d} x[src_e]            (slab gather, fp16 data, fp32 accum)
//   out   = relu([hx | x] @ Wt^T + bu + (deg+1)*dvec) (fp16 MFMA, fp32 accum)
// Wt[n][k] = k<64 ? (Wm@Wu_top)[k][n] : Wu_bot[k-64][n]   (fp16, precomputed)
//
// Learned constraints:
//  - NO min-waves launch bound on register-heavy kernels (r4: spill to scratch).
//  - Do NOT fuse latency-bound gather with the MFMA update (r9: +47us/layer).
//  - MFMA A/B share the (g=lane>>4, j) -> k map: feeding both with f(g,j)=8g+j
//    (contiguous 16B) computes exact A*B. C/D: col=lane&15, row=4*(lane>>4)+reg.
//  - LDS A-tile rows stride 128B = same-bank; XOR-swizzle 16B-chunk ^= (row&7).
//  - XCD-partitioning the scattered fill gave ~0 (r7-r10) -> dropped.
//  - rocprof per-dispatch us of tiny dispatches is serialization-inflated (r8);
//    harness 256MB poison fills own the top-5 -> use dur_us deltas only.
//  - Per-lane arrays must be statically indexed or they spill to scratch.
//  - Slab-CSR (this round): slab[node*64+slot], slot=atomicAdd(cursor) in ONE
//    pass = deg+fill merged, no scans, gather index addr = f(node) (no rowptr
//    dep). Overflow (deg>64, ~never) -> list + CAS fixup for correctness.

#define DIM 64

typedef _Float16 f16x8 __attribute__((ext_vector_type(8)));
typedef float f32x4 __attribute__((ext_vector_type(4)));

static __device__ __forceinline__ float lo16(unsigned u) {
  return __half2float(__ushort_as_half((unsigned short)(u & 0xFFFFu)));
}
static __device__ __forceinline__ float hi16(unsigned u) {
  return __half2float(__ushort_as_half((unsigned short)(u >> 16)));
}
static __device__ __forceinline__ unsigned pack16(float a, float b) {
  return (unsigned)__half_as_ushort(__float2half(a)) |
         ((unsigned)__half_as_ushort(__float2half(b)) << 16);
}

// blocks 0..2: fused fp16 weights per layer.  blocks 3..: zero cursor+ovfcnt.
__global__ __launch_bounds__(256) void fuse_weights_kernel(
    const float* __restrict__ Wm0, const float* __restrict__ bm0, const float* __restrict__ Wu0,
    const float* __restrict__ Wm1, const float* __restrict__ bm1, const float* __restrict__ Wu1,
    const float* __restrict__ Wm2, const float* __restrict__ bm2, const float* __restrict__ Wu2,
    unsigned short* __restrict__ Wtb, float* __restrict__ dv,
    int* __restrict__ cursor, int n) {
  const int l = blockIdx.x;
  if (l >= 3) {
    const int nq = (n >> 2) + 1;  // covers cursor[n] + ovfcnt + pad
    const int t0 = (l - 3) * 256 + threadIdx.x;
    const int stride = (gridDim.x - 3) * 256;
    int4* d4 = (int4*)cursor;
    for (int i = t0; i < nq; i += stride) d4[i] = make_int4(0, 0, 0, 0);
    return;
  }
  const float* Wm = l == 0 ? Wm0 : l == 1 ? Wm1 : Wm2;
  const float* bm = l == 0 ? bm0 : l == 1 ? bm1 : bm2;
  const float* Wu = l == 0 ? Wu0 : l == 1 ? Wu1 : Wu2;
  __shared__ float sWm[4096];
  __shared__ float sWu[4096];   // top half of Wu (rows 0..63)
  __shared__ float sW1[4096];   // Wm @ Wu_top
  const int tid = threadIdx.x;
  for (int i = tid; i < 4096; i += 256) {
    sWm[i] = Wm[i];
    sWu[i] = Wu[i];
  }
  __syncthreads();
  for (int i = tid; i < 4096; i += 256) {
    const int r = i >> 6, c = i & 63;
    float acc = 0.f;
#pragma unroll
    for (int k = 0; k < 64; ++k) acc = fmaf(sWm[r * 64 + k], sWu[k * 64 + c], acc);
    sW1[i] = acc;
  }
  __syncthreads();
  unsigned short* Wl = Wtb + (size_t)l * 8192;
  for (int i = tid; i < 8192; i += 256) {
    const int ncol = i >> 7, k = i & 127;
    const float v = (k < 64) ? sW1[k * 64 + ncol] : Wu[k * 64 + ncol];
    Wl[i] = __half_as_ushort(__float2half(v));
  }
  if (tid < 64) {
    float acc = 0.f;
#pragma unroll
    for (int k = 0; k < 64; ++k) acc = fmaf(bm[k], sWu[k * 64 + tid], acc);
    dv[l * 64 + tid] = acc;
  }
}

// Merged one-pass prep: fp32->fp16 convert of x + slab-CSR build.
// slot = atomicAdd(cursor[dst]) gives BOTH the slab slot and (finally) deg.
__global__ __launch_bounds__(256) void prep_kernel(
    const float* __restrict__ x, unsigned* __restrict__ xb2, int nquads,
    const int* __restrict__ src, const int* __restrict__ dst,
    int* __restrict__ cursor, unsigned short* __restrict__ slab,
    unsigned* __restrict__ ovf, int* __restrict__ ovfcnt, int Epairs, int Ecap) {
  const int gsz = gridDim.x * 256;
  for (int i = blockIdx.x * 256 + threadIdx.x; i < nquads; i += gsz) {
    const float4 v = ((const float4*)x)[i];
    xb2[2 * i] = pack16(v.x, v.y);
    xb2[2 * i + 1] = pack16(v.z, v.w);
  }
  for (int t = blockIdx.x * 256 + threadIdx.x; t < Epairs; t += gsz) {
    const int2 d2 = ((const int2*)dst)[t];
    const int2 s2 = ((const int2*)src)[t];
    const int p0 = atomicAdd(&cursor[d2.x], 1);
    if (p0 < 64) {
      slab[(unsigned)d2.x * 64 + p0] = (unsigned short)s2.x;
    } else {
      const int o = atomicAdd(ovfcnt, 1);
      if (o < Ecap) ovf[o] = ((unsigned)d2.x << 16) | (unsigned)s2.x;
    }
    const int p1 = atomicAdd(&cursor[d2.y], 1);
    if (p1 < 64) {
      slab[(unsigned)d2.y * 64 + p1] = (unsigned short)s2.y;
    } else {
      const int o = atomicAdd(ovfcnt, 1);
      if (o < Ecap) ovf[o] = ((unsigned)d2.y << 16) | (unsigned)s2.y;
    }
  }
}

// One wave per node. Quarter-wave q=lane>>4 picks the neighbor; 16 lanes x
// uint2 (8B) = one 128B fp16 row -> 4 neighbor rows per load instruction.
// Index load is coalesced from slab[node*64+lane] (no rowptr dependency).
#define GRP(II)                                                        \
  {                                                                    \
    const int t0 = __builtin_amdgcn_readlane(myi, (II));               \
    const int t1 = __builtin_amdgcn_readlane(myi, (II) + 1);           \
    const int t2 = __builtin_amdgcn_readlane(myi, (II) + 2);           \
    const int t3 = __builtin_amdgcn_readlane(myi, (II) + 3);           \
    const int ta = (q & 1) ? t1 : t0;                                  \
    const int tb = (q & 1) ? t3 : t2;                                  \
    const int s = (q & 2) ? tb : ta;                                   \
    const uint2 u = xu2[(unsigned)s * 16 + j16];                       \
    a0 += lo16(u.x); a1 += hi16(u.x);                                  \
    a2 += lo16(u.y); a3 += hi16(u.y);                                  \
  }

__global__ __launch_bounds__(256, 8) void gather_kernel(
    const unsigned* __restrict__ xu,   // fp16 x, 32 uints/row
    const unsigned short* __restrict__ slab, const int* __restrict__ degp,
    unsigned* __restrict__ hxu, int n) {
  const int lane = threadIdx.x & 63;
  const int q = lane >> 4, j16 = lane & 15;
  const uint2* xu2 = (const uint2*)xu;
  uint2* hxu2 = (uint2*)hxu;
  const int wid = (blockIdx.x * 256 + threadIdx.x) >> 6;
  const int nwaves = (gridDim.x * 256) >> 6;
  for (int node = wid; node < n; node += nwaves) {
    const int nodeu = __builtin_amdgcn_readfirstlane(node);
    const int cnt = degp[nodeu];
    const int c64 = cnt > 64 ? 64 : cnt;
    int myi = 0;
    if (lane < c64) myi = (int)slab[(unsigned)nodeu * 64 + lane];
    float a0 = 0.f, a1 = 0.f, a2 = 0.f, a3 = 0.f;
    int i = 0;
    for (; i + 15 < c64; i += 16) {  // 4 loads in flight, 16 neighbors
      GRP(i) GRP(i + 4) GRP(i + 8) GRP(i + 12)
    }
    for (; i + 3 < c64; i += 4) { GRP(i) }
    const int rem = c64 - i;
    if (q < rem) { GRP(i) }            // readlanes past c64 unused by active lanes
    if (q == 0) {                      // self row
      const uint2 u = xu2[(unsigned)nodeu * 16 + j16];
      a0 += lo16(u.x); a1 += hi16(u.x);
      a2 += lo16(u.y); a3 += hi16(u.y);
    }
    a0 += __shfl_xor(a0, 16, 64); a0 += __shfl_xor(a0, 32, 64);
    a1 += __shfl_xor(a1, 16, 64); a1 += __shfl_xor(a1, 32, 64);
    a2 += __shfl_xor(a2, 16, 64); a2 += __shfl_xor(a2, 32, 64);
    a3 += __shfl_xor(a3, 16, 64); a3 += __shfl_xor(a3, 32, 64);
    if (q == 0)
      hxu2[(unsigned)nodeu * 16 + j16] = make_uint2(pack16(a0, a1), pack16(a2, a3));
  }
}

// Overflow fixup (deg>64 tail edges; ~never executed): CAS-add the fp16x2 row.
__global__ __launch_bounds__(256) void fixup_kernel(
    const unsigned* __restrict__ xu, const unsigned* __restrict__ ovf,
    const int* __restrict__ ovfcnt, unsigned* __restrict__ hxu, int Ecap) {
  int cnt = *ovfcnt;
  if (cnt > Ecap) cnt = Ecap;
  const int j = threadIdx.x & 31;
  const int half = (blockIdx.x * 256 + threadIdx.x) >> 5;
  const int nhalf = (gridDim.x * 256) >> 5;
  for (int e = half; e < cnt; e += nhalf) {
    const unsigned v = ovf[e];
    const unsigned d = v >> 16, s = v & 0xFFFFu;
    unsigned* p = &hxu[d * 32 + j];
    const unsigned add = xu[s * 32 + j];
    unsigned old = *(volatile unsigned*)p;
    while (true) {
      const unsigned nw = pack16(lo16(old) + lo16(add), hi16(old) + hi16(add));
      const unsigned prev = atomicCAS(p, old, nw);
      if (prev == old) break;
      old = prev;
    }
  }
}

// 64 rows per block (4 waves x 16). A = [hx | x] (K=128) staged in swizzled
// LDS; B = Wt[n][k] fragments loaded as contiguous 16B; 16 MFMAs per wave.
template <int OUT_F32>
__global__ __launch_bounds__(256) void gemm_kernel(
    const unsigned short* __restrict__ hxb, const unsigned short* __restrict__ xb,
    const unsigned short* __restrict__ Wtb, const float* __restrict__ bu,
    const float* __restrict__ dvec, const int* __restrict__ deg,
    void* __restrict__ outp, int n) {
  __shared__ unsigned short lhx[64 * 64];
  __shared__ unsigned short lx[64 * 64];
  const int tid = threadIdx.x;
  const int base = blockIdx.x * 64;
  {
    const uint4* ghx = (const uint4*)hxb;
    const uint4* gx = (const uint4*)xb;
    uint4* shx = (uint4*)lhx;
    uint4* sx = (uint4*)lx;
    for (int t = tid; t < 512; t += 256) {
      const int row = t >> 3, c = t & 7;
      const int grow = base + row;
      uint4 vh = make_uint4(0, 0, 0, 0), vx = make_uint4(0, 0, 0, 0);
      if (grow < n) {
        vh = ghx[(size_t)grow * 8 + c];
        vx = gx[(size_t)grow * 8 + c];
      }
      const int cs = c ^ (row & 7);
      shx[row * 8 + cs] = vh;
      sx[row * 8 + cs] = vx;
    }
  }
  const int lane = tid & 63;
  const int w = tid >> 6;
  const int l15 = lane & 15, lg = lane >> 4;
  f16x8 bfr[16];
#pragma unroll
  for (int ct = 0; ct < 4; ++ct)
#pragma unroll
    for (int kq = 0; kq < 4; ++kq)
      bfr[ct * 4 + kq] = *(const f16x8*)((const char*)Wtb + (ct * 16 + l15) * 256 + kq * 64 + lg * 16);
  __syncthreads();
  f32x4 acc[4] = {0, 0, 0, 0};
  const int rt = w * 16 + l15;
#pragma unroll
  for (int kq = 0; kq < 4; ++kq) {
    const unsigned short* mat = (kq < 2) ? lhx : lx;
    const int chunk = lg + 4 * (kq & 1);
    const int cs = chunk ^ (rt & 7);
    const f16x8 af = *(const f16x8*)((const char*)mat + rt * 128 + cs * 16);
#pragma unroll
    for (int ct = 0; ct < 4; ++ct)
      acc[ct] = __builtin_amdgcn_mfma_f32_16x16x32_f16(af, bfr[ct * 4 + kq], acc[ct], 0, 0, 0);
  }
#pragma unroll
  for (int r = 0; r < 4; ++r) {
    const int row = base + w * 16 + lg * 4 + r;
    if (row < n) {
      const float dg = (float)(deg[row] + 1);
#pragma unroll
      for (int ct = 0; ct < 4; ++ct) {
        const int col = ct * 16 + l15;
        float v = acc[ct][r] + bu[col] + dg * dvec[col];
        v = v > 0.f ? v : 0.f;
        if (OUT_F32)
          ((float*)outp)[(size_t)row * 64 + col] = v;
        else
          ((unsigned short*)outp)[(size_t)row * 64 + col] = __half_as_ushort(__float2half(v));
      }
    }
  }
}

extern "C" void kernel_launch(void* const* d_in, const int* in_sizes, int n_in,
                              void* d_out, int out_size, void* d_ws, size_t ws_size,
                              hipStream_t stream) {
  const float* x = (const float*)d_in[0];
  const int* ei = (const int*)d_in[1];
  const int n = in_sizes[0] / DIM;   // 50000
  const int E = in_sizes[1] / 2;     // 800000
  const int* srcp = ei;
  const int* dstp = ei + E;

  // Workspace layout (16B alignment maintained; n%4==0, E even)
  unsigned short* xb = (unsigned short*)d_ws;        // n*64 fp16
  unsigned short* hxb = xb + (size_t)n * DIM;        // n*64 fp16
  unsigned short* yb = hxb + (size_t)n * DIM;        // n*64 fp16
  unsigned short* Wtb = yb + (size_t)n * DIM;        // 3*8192 fp16
  unsigned short* slab = Wtb + 3 * 8192;             // n*64 ushort
  float* dv = (float*)(slab + (size_t)n * DIM);      // 3*64
  int* cursor = (int*)(dv + 3 * 64);                 // n (+ ovfcnt + pad)
  int* ovfcnt = cursor + n;                          // 1 (+3 pad)
  unsigned* ovf = (unsigned*)(cursor + n + 4);       // E

  // One-time prep: fused fp16 weights + cursor/ovfcnt zeroing (spare blocks);
  // then one-pass convert + slab-CSR build.
  fuse_weights_kernel<<<32, 256, 0, stream>>>(
      (const float*)d_in[2], (const float*)d_in[3], (const float*)d_in[4],
      (const float*)d_in[6], (const float*)d_in[7], (const float*)d_in[8],
      (const float*)d_in[10], (const float*)d_in[11], (const float*)d_in[12],
      Wtb, dv, cursor, n);
  const int nquads = n * DIM / 4;
  prep_kernel<<<1024, 256, 0, stream>>>(x, (unsigned*)xb, nquads, srcp, dstp,
                                        cursor, slab, ovf, ovfcnt, E / 2, E);

  // Layer chain (fp16): xb -> yb -> xb -> d_out(fp32)
  const int gblocks = (n + 63) / 64;
  gather_kernel<<<2048, 256, 0, stream>>>((const unsigned*)xb, slab, cursor, (unsigned*)hxb, n);
  fixup_kernel<<<8, 256, 0, stream>>>((const unsigned*)xb, ovf, ovfcnt, (unsigned*)hxb, E);
  gemm_kernel<0><<<gblocks, 256, 0, stream>>>(hxb, xb, Wtb, (const float*)d_in[5], dv, cursor, yb, n);
  gather_kernel<<<2048, 256, 0, stream>>>((const unsigned*)yb, slab, cursor, (unsigned*)hxb, n);
  fixup_kernel<<<8, 256, 0, stream>>>((const unsigned*)yb, ovf, ovfcnt, (unsigned*)hxb, E);
  gemm_kernel<0><<<gblocks, 256, 0, stream>>>(hxb, yb, Wtb + 8192, (const float*)d_in[9], dv + 64, cursor, xb, n);
  gather_kernel<<<2048, 256, 0, stream>>>((const unsigned*)xb, slab, cursor, (unsigned*)hxb, n);
  fixup_kernel<<<8, 256, 0, stream>>>((const unsigned*)xb, ovf, ovfcnt, (unsigned*)hxb, E);
  gemm_kernel<1><<<gblocks, 256, 0, stream>>>(hxb, xb, Wtb + 16384, (const float*)d_in[13], dv + 128, cursor, d_out, n);
}